// Round 9
// baseline (120.418 us; speedup 1.0000x reference)
//
#include <hip/hip_runtime.h>
#include <type_traits>
#include <utility>

#define NT 2048   // tokens
#define HD 1024   // hidden
#define NHEAD 16
#define DHEAD 64
#define LOG2E 1.44269504f

typedef float f32x4 __attribute__((ext_vector_type(4)));
typedef __bf16 b16x8 __attribute__((ext_vector_type(8)));
typedef short s16x8 __attribute__((ext_vector_type(8)));
typedef unsigned short u16x8 __attribute__((ext_vector_type(8)));
typedef unsigned short u16x4 __attribute__((ext_vector_type(4)));

// ---- MFMA builtin signature dispatch (bf16-vector vs short-vector toolchains) ----
template <typename V, typename = void>
struct mfma_takes : std::false_type {};
template <typename V>
struct mfma_takes<V, std::void_t<decltype(__builtin_amdgcn_mfma_f32_16x16x32_bf16(
                         std::declval<V>(), std::declval<V>(), std::declval<f32x4>(), 0, 0, 0))>>
    : std::true_type {};

template <typename V>
__device__ __forceinline__ f32x4 mfma_impl(V a, V b, f32x4 c) {
  return __builtin_amdgcn_mfma_f32_16x16x32_bf16(a, b, c, 0, 0, 0);
}

__device__ __forceinline__ f32x4 mfma_bf16(u16x8 a, u16x8 b, f32x4 c) {
  using V = typename std::conditional<mfma_takes<b16x8>::value, b16x8, s16x8>::type;
  return mfma_impl<V>(__builtin_bit_cast(V, a), __builtin_bit_cast(V, b), c);
}

__device__ __forceinline__ unsigned short f2bf(float f) {
  unsigned int u = __builtin_bit_cast(unsigned int, f);
  return (unsigned short)((u + 0x7FFFu + ((u >> 16) & 1u)) >> 16);
}

// async global->LDS, 16B per lane
__device__ __forceinline__ void gload16(const unsigned short* g, unsigned short* l) {
  __builtin_amdgcn_global_load_lds(
      (__attribute__((address_space(1))) void*)(void*)(g),
      (__attribute__((address_space(3))) void*)(void*)(l), 16, 0, 0);
}

// raw barrier pinned against compile-time motion of LDS/VMEM ops
__device__ __forceinline__ void barrier_pinned() {
  __builtin_amdgcn_sched_barrier(0);
  __builtin_amdgcn_s_barrier();
  __builtin_amdgcn_sched_barrier(0);
}
#define WAIT_VM8() asm volatile("s_waitcnt vmcnt(8)" ::: "memory")
#define WAIT_VM4() asm volatile("s_waitcnt vmcnt(4)" ::: "memory")
#define WAIT_VM0() asm volatile("s_waitcnt vmcnt(0)" ::: "memory")
#define WAIT_LGKM0() asm volatile("s_waitcnt lgkmcnt(0)" ::: "memory")

// =====================================================================
// Kernel 0: fp32 -> bf16 conversion of the 4 weight matrices only
// (q/k/v conversion is fused into proj_gemm's A-staging).
// grid = (512, 4); each seg is HD*HD.
// =====================================================================
__global__ __launch_bounds__(256) void cvt_bf16(
    const float* __restrict__ s0, const float* __restrict__ s1, const float* __restrict__ s2,
    const float* __restrict__ s3,
    unsigned short* __restrict__ d0, unsigned short* __restrict__ d1,
    unsigned short* __restrict__ d2, unsigned short* __restrict__ d3) {
  const int seg = blockIdx.y;
  const float* s;
  unsigned short* d;
  switch (seg) {
    case 0: s = s0; d = d0; break;
    case 1: s = s1; d = d1; break;
    case 2: s = s2; d = d2; break;
    default: s = s3; d = d3; break;
  }
  const int i = blockIdx.x * 2048 + threadIdx.x * 8;
  f32x4 f0 = *reinterpret_cast<const f32x4*>(&s[i]);
  f32x4 f1 = *reinterpret_cast<const f32x4*>(&s[i + 4]);
  u16x8 o;
#pragma unroll
  for (int e = 0; e < 4; ++e) { o[e] = f2bf(f0[e]); o[e + 4] = f2bf(f1[e]); }
  *reinterpret_cast<u16x8*>(&d[i]) = o;
}

// =====================================================================
// Kernel 1: fused QKV projection with inline fp32->bf16 A-conversion.
// 1D grid 768: L = m*96 + z*32 + n (L%8 = n%8 -> A-panel shares an XCD).
// A (q/k/v) fp32: reg-loaded, converted, ds_written. B (weights) bf16 via
// global_load_lds. Ledger rule: finishA(s+1) BEFORE issueA(s+2) — areg is
// a single register set, consume before overwrite (R8 bug).
// z=0: Q scaled by 0.125*log2e row-major; z=1: K row-major; z=2: V transposed.
// =====================================================================
__global__ __launch_bounds__(256) void proj_gemm(
    const float* __restrict__ qf32, const float* __restrict__ kf32,
    const float* __restrict__ vf32,
    const unsigned short* __restrict__ Wqb, const unsigned short* __restrict__ Wkb,
    const unsigned short* __restrict__ Wvb,
    const float* __restrict__ bq, const float* __restrict__ bk, const float* __restrict__ bv,
    unsigned short* __restrict__ Qh, unsigned short* __restrict__ Kh,
    unsigned short* __restrict__ Vt) {
  const int L = blockIdx.x;
  const int m = L / 96;
  const int c = L % 96;
  const int z = c / 32;
  const int n = c % 32;
  const int n0 = n * 64, m0 = m * 128;

  const float* A = (z == 0) ? qf32 : (z == 1) ? kf32 : vf32;
  const unsigned short* B = (z == 0) ? Wqb : (z == 1) ? Wkb : Wvb;
  const float* bias = (z == 0) ? bq : (z == 1) ? bk : bv;

  __shared__ unsigned short As0[64 * 64], As1[64 * 64];
  __shared__ unsigned short Bs0[128 * 64], Bs1[128 * 64];

  const int tid = threadIdx.x;
  const int lane = tid & 63;
  const int wr = (tid >> 6) >> 1, wc = (tid >> 6) & 1;
  const int srow = tid >> 3;                              // 0..31
  const int schk = (tid & 7) ^ (srow & 7);                // swizzled chunk idx
  const int scol = schk << 3;                             // element offset

  f32x4 areg[4];  // in-flight fp32 A data (2 chunks x 2 f32x4)

  auto issueA = [&](int kt) {
#pragma unroll
    for (int p = 0; p < 2; ++p) {
      const float* src = &A[(size_t)(n0 + p * 32 + srow) * HD + kt + scol];
      areg[p * 2 + 0] = *reinterpret_cast<const f32x4*>(src);
      areg[p * 2 + 1] = *reinterpret_cast<const f32x4*>(src + 4);
    }
  };
  auto finishA = [&](unsigned short* as) {
#pragma unroll
    for (int p = 0; p < 2; ++p) {
      u16x8 o;
#pragma unroll
      for (int e = 0; e < 4; ++e) {
        o[e] = f2bf(areg[p * 2 + 0][e]);
        o[e + 4] = f2bf(areg[p * 2 + 1][e]);
      }
      *reinterpret_cast<u16x8*>(&as[p * 2048 + tid * 8]) = o;
    }
  };
  auto issueB = [&](int kt, unsigned short* bs) {
#pragma unroll
    for (int p = 0; p < 4; ++p)
      gload16(&B[(size_t)(m0 + p * 32 + srow) * HD + kt + scol], bs + p * 2048 + tid * 8);
  };
  f32x4 acc[2][4] = {};
  auto comp = [&](const unsigned short* as, const unsigned short* bs) {
#pragma unroll
    for (int ks = 0; ks < 2; ++ks) {
      const int q = ks * 4 + (lane >> 4);  // 16B-chunk index 0..7
      u16x8 a[2], b[4];
#pragma unroll
      for (int i = 0; i < 2; ++i) {
        const int row = wr * 32 + i * 16 + (lane & 15);
        a[i] = *reinterpret_cast<const u16x8*>(&as[row * 64 + ((q ^ (row & 7)) << 3)]);
      }
#pragma unroll
      for (int j = 0; j < 4; ++j) {
        const int row = wc * 64 + j * 16 + (lane & 15);
        b[j] = *reinterpret_cast<const u16x8*>(&bs[row * 64 + ((q ^ (row & 7)) << 3)]);
      }
#pragma unroll
      for (int i = 0; i < 2; ++i)
#pragma unroll
        for (int j = 0; j < 4; ++j)
          acc[i][j] = mfma_bf16(a[i], b[j], acc[i][j]);
    }
  };

  // ---- prologue (issue order: A0, B0, A1, B1) ----
  issueA(0);               // outst: A0 (4)
  issueB(0, Bs0);          // outst: A0,B0 (8)
  WAIT_VM4();              // A0 done (B0 in flight)
  finishA(As0);            // A0 -> As0 (areg free)
  issueA(64);              // outst: B0,A1 (8)
  issueB(64, Bs1);         // outst: B0,A1,B1 (12)

#pragma unroll 1
  for (int s = 0; s < 14; ++s) {
    WAIT_VM8();            // B(s) gload_lds complete; outst: A(s+1),B(s+1) (8)
    WAIT_LGKM0();          // this wave's A(s) ds_writes complete
    barrier_pinned();      // all waves' stage-s data visible
    if (s & 1) comp(As1, Bs1); else comp(As0, Bs0);
    barrier_pinned();      // all waves done reading buffers (s&1)
    WAIT_VM4();            // A(s+1) reg-loads complete; outst: B(s+1) (4)
    finishA((s & 1) ? As0 : As1);  // A(s+1) -> buf[(s+1)&1]  (consume areg BEFORE reissue)
    issueA((s + 2) * 64);          // outst: B(s+1),A(s+2) (8)
    issueB((s + 2) * 64, (s & 1) ? Bs1 : Bs0);  // outst: B(s+1),A(s+2),B(s+2) (12)
  }
  // epilogue: outst = B(14),A(15),B(15)
  WAIT_VM8();              // B(14) done
  WAIT_LGKM0();
  barrier_pinned();
  comp(As0, Bs0);          // stage 14 (buf 0)
  barrier_pinned();
  WAIT_VM4();              // A(15) done (B(15) in flight)
  finishA(As1);
  WAIT_VM0();              // B(15) done
  WAIT_LGKM0();
  barrier_pinned();
  comp(As1, Bs1);

  const int rgrp = (lane >> 4) * 4;
  const float scale = (z == 0) ? 0.125f * LOG2E : 1.0f;
#pragma unroll
  for (int i = 0; i < 2; ++i) {
    const int nb = n0 + wr * 32 + i * 16 + rgrp;
#pragma unroll
    for (int j = 0; j < 4; ++j) {
      const int mcol = m0 + wc * 64 + j * 16 + (lane & 15);
      const float bb = bias[mcol];
      if (z == 2) {
        u16x4 pk;
#pragma unroll
        for (int r = 0; r < 4; ++r) pk[r] = f2bf(acc[i][j][r] + bb);
        *reinterpret_cast<u16x4*>(&Vt[(size_t)mcol * NT + nb]) = pk;  // transposed store
      } else {
        unsigned short* dst = (z == 0) ? Qh : Kh;
#pragma unroll
        for (int r = 0; r < 4; ++r)
          dst[(size_t)(nb + r) * HD + mcol] = f2bf((acc[i][j][r] + bb) * scale);
      }
    }
  }
}

// =====================================================================
// Kernel 2: flash attention with additive bias (log2-domain softmax).
// 1D grid 512: xcd = id&7 owns heads {2*xcd, 2*xcd+1} (K/V L2 locality).
// 256 threads = 4 waves x 16 q-rows. K/V double-buffered via
// global_load_lds (linear LDS + XOR-swizzled global source); one
// vmcnt(0)+barrier per iteration. 80KB LDS -> 2 blocks/CU.
// =====================================================================
__global__ __launch_bounds__(256, 2) void attn_kernel(
    const unsigned short* __restrict__ Qh, const unsigned short* __restrict__ Kh,
    const unsigned short* __restrict__ Vt, const float* __restrict__ bias,
    unsigned short* __restrict__ ctx) {
  const int id = blockIdx.x;
  const int xcd = id & 7, slot = id >> 3;
  const int h = xcd * 2 + (slot >> 5);
  const int q0 = (slot & 31) * 64;
  const int tid = threadIdx.x;
  const int lane = tid & 63;
  const int wave = tid >> 6;

  __shared__ unsigned short Ks0[128 * 64], Ks1[128 * 64];   // 16KB each
  __shared__ unsigned short Vs0[64 * 128], Vs1[64 * 128];   // 16KB each
  __shared__ unsigned short Ps[4 * 16 * 128];               // 16KB  => 80KB total

  u16x8 qf[2];
  {
    const int qrow = q0 + wave * 16 + (lane & 15);
    const int db = (lane >> 4) * 8;
    qf[0] = *reinterpret_cast<const u16x8*>(&Qh[(size_t)qrow * HD + h * DHEAD + db]);
    qf[1] = *reinterpret_cast<const u16x8*>(&Qh[(size_t)qrow * HD + h * DHEAD + 32 + db]);
  }

  f32x4 oacc[4] = {};
  float mrun[4], lrun[4];
#pragma unroll
  for (int r = 0; r < 4; ++r) { mrun[r] = -3.0e38f; lrun[r] = 0.f; }

  const float* bias_h = bias + (size_t)h * NT * NT;
  const int qlrow = q0 + wave * 16 + (lane >> 4) * 4;  // + r
  const float* bias_l = bias_h + (size_t)qlrow * NT + (lane & 15);

  const unsigned short* Kbase = Kh + h * DHEAD;
  const unsigned short* Vbase = Vt + (size_t)h * DHEAD * NT;

  const int krow = tid >> 3;
  const int kchk = tid & 7;
  const int vrow = tid >> 4;
  const int vchk = tid & 15;

  auto stage = [&](int t, unsigned short* ks, unsigned short* vs) {
    const int kt = t * 128;
#pragma unroll
    for (int p = 0; p < 4; ++p) {
      const int r = p * 32 + krow;
      gload16(&Kbase[(size_t)(kt + r) * HD + ((kchk ^ (r & 7)) << 3)], ks + p * 2048 + tid * 8);
    }
#pragma unroll
    for (int p = 0; p < 4; ++p) {
      const int r = p * 16 + vrow;
      gload16(&Vbase[(size_t)r * NT + kt + ((vchk ^ (r & 7)) << 3)], vs + p * 2048 + tid * 8);
    }
  };

  float br[8][4];
#pragma unroll
  for (int j = 0; j < 8; ++j)
#pragma unroll
    for (int r = 0; r < 4; ++r) br[j][r] = bias_l[(size_t)r * NT + j * 16];
  stage(0, Ks0, Vs0);
  WAIT_VM0();
  barrier_pinned();

  unsigned short* const psw = Ps + wave * 2048;

#pragma unroll 1
  for (int t = 0; t < NT / 128; ++t) {
    const bool more = (t + 1 < NT / 128);
    const unsigned short* ks = (t & 1) ? Ks1 : Ks0;
    const unsigned short* vs = (t & 1) ? Vs1 : Vs0;

    if (more) stage(t + 1, (t & 1) ? Ks0 : Ks1, (t & 1) ? Vs0 : Vs1);

    // ---- QK^T (Q pre-scaled by 0.125*log2e) ----
    f32x4 s[8] = {};
#pragma unroll
    for (int kss = 0; kss < 2; ++kss) {
      const int q = kss * 4 + (lane >> 4);
#pragma unroll
      for (int j = 0; j < 8; ++j) {
        const int row = j * 16 + (lane & 15);
        u16x8 kf = *reinterpret_cast<const u16x8*>(&ks[row * 64 + ((q ^ (row & 7)) << 3)]);
        s[j] = mfma_bf16(qf[kss], kf, s[j]);
      }
    }
#pragma unroll
    for (int j = 0; j < 8; ++j)
#pragma unroll
      for (int r = 0; r < 4; ++r) s[j][r] = fmaf(br[j][r], LOG2E, s[j][r]);

    if (more) {
      const float* bp = bias_l + (size_t)(t + 1) * 128;
#pragma unroll
      for (int j = 0; j < 8; ++j)
#pragma unroll
        for (int r = 0; r < 4; ++r) br[j][r] = bp[(size_t)r * NT + j * 16];
    }

    // ---- online softmax (log2 domain) ----
    float mnew[4];
#pragma unroll
    for (int r = 0; r < 4; ++r) {
      float mx = s[0][r];
#pragma unroll
      for (int j = 1; j < 8; ++j) mx = fmaxf(mx, s[j][r]);
      mx = fmaxf(mx, __shfl_xor(mx, 1));
      mx = fmaxf(mx, __shfl_xor(mx, 2));
      mx = fmaxf(mx, __shfl_xor(mx, 4));
      mx = fmaxf(mx, __shfl_xor(mx, 8));
      mnew[r] = fmaxf(mrun[r], mx);
    }
#pragma unroll
    for (int r = 0; r < 4; ++r) {
      const float corr = exp2f(mrun[r] - mnew[r]);
      lrun[r] *= corr;
#pragma unroll
      for (int nd = 0; nd < 4; ++nd) oacc[nd][r] *= corr;
      mrun[r] = mnew[r];
    }
    float psum[4] = {0.f, 0.f, 0.f, 0.f};
#pragma unroll
    for (int j = 0; j < 8; ++j) {
      const int chkbase = j * 2 + ((lane >> 3) & 1);
      const int cofs = lane & 7;
#pragma unroll
      for (int r = 0; r < 4; ++r) {
        const int row = (lane >> 4) * 4 + r;
        const float p = exp2f(s[j][r] - mrun[r]);
        psum[r] += p;
        psw[row * 128 + ((chkbase ^ (row & 7)) << 3) + cofs] = f2bf(p);
      }
    }
#pragma unroll
    for (int r = 0; r < 4; ++r) {
      float tsum = psum[r];
      tsum += __shfl_xor(tsum, 1);
      tsum += __shfl_xor(tsum, 2);
      tsum += __shfl_xor(tsum, 4);
      tsum += __shfl_xor(tsum, 8);
      lrun[r] += tsum;
    }

    // ---- PV ----
#pragma unroll
    for (int kk = 0; kk < 4; ++kk) {
      const int q = kk * 4 + (lane >> 4);
      const int prow = lane & 15;
      u16x8 pa = *reinterpret_cast<const u16x8*>(&psw[prow * 128 + ((q ^ (prow & 7)) << 3)]);
#pragma unroll
      for (int nd = 0; nd < 4; ++nd) {
        const int vr = nd * 16 + (lane & 15);
        u16x8 vb = *reinterpret_cast<const u16x8*>(&vs[vr * 128 + ((q ^ (vr & 7)) << 3)]);
        oacc[nd] = mfma_bf16(pa, vb, oacc[nd]);
      }
    }

    WAIT_VM0();
    barrier_pinned();
  }

#pragma unroll
  for (int nd = 0; nd < 4; ++nd) {
#pragma unroll
    for (int r = 0; r < 4; ++r) {
      const float val = oacc[nd][r] / lrun[r];
      ctx[(size_t)(qlrow + r) * HD + h * DHEAD + nd * 16 + (lane & 15)] = f2bf(val);
    }
  }
}

// =====================================================================
// Kernel 3: output projection, fp32 out. 64x64 tiles, 1D grid 512:
// L = m*32 + n (L%8 = n%8 XCD grouping). 2 blocks/CU. vmcnt(4) pipeline.
// =====================================================================
__global__ __launch_bounds__(256) void out_gemm(
    const unsigned short* __restrict__ Ain, const unsigned short* __restrict__ Wob,
    const float* __restrict__ bias, float* __restrict__ out) {
  const int L = blockIdx.x;
  const int m = L / 32;
  const int n = L % 32;
  const int n0 = n * 64, m0 = m * 64;

  __shared__ unsigned short As0[64 * 64], As1[64 * 64];
  __shared__ unsigned short Bs0[64 * 64], Bs1[64 * 64];

  const int tid = threadIdx.x;
  const int lane = tid & 63;
  const int wr = (tid >> 6) >> 1, wc = (tid >> 6) & 1;
  const int srow = tid >> 3;                              // 0..31
  const int scol = (((tid & 7) ^ (srow & 7)) << 3);       // swizzled source chunk

  auto stage = [&](int kt, unsigned short* as, unsigned short* bs) {
#pragma unroll
    for (int p = 0; p < 2; ++p)
      gload16(&Ain[(size_t)(n0 + p * 32 + srow) * HD + kt + scol], as + p * 2048 + tid * 8);
#pragma unroll
    for (int p = 0; p < 2; ++p)
      gload16(&Wob[(size_t)(m0 + p * 32 + srow) * HD + kt + scol], bs + p * 2048 + tid * 8);
  };
  f32x4 acc[2][2] = {};
  auto comp = [&](const unsigned short* as, const unsigned short* bs) {
#pragma unroll
    for (int ks = 0; ks < 2; ++ks) {
      const int q = ks * 4 + (lane >> 4);
      u16x8 a[2], b[2];
#pragma unroll
      for (int i = 0; i < 2; ++i) {
        const int row = wr * 32 + i * 16 + (lane & 15);
        a[i] = *reinterpret_cast<const u16x8*>(&as[row * 64 + ((q ^ (row & 7)) << 3)]);
      }
#pragma unroll
      for (int j = 0; j < 2; ++j) {
        const int row = wc * 32 + j * 16 + (lane & 15);
        b[j] = *reinterpret_cast<const u16x8*>(&bs[row * 64 + ((q ^ (row & 7)) << 3)]);
      }
#pragma unroll
      for (int i = 0; i < 2; ++i)
#pragma unroll
        for (int j = 0; j < 2; ++j)
          acc[i][j] = mfma_bf16(a[i], b[j], acc[i][j]);
    }
  };

  stage(0, As0, Bs0);
  stage(64, As1, Bs1);
#pragma unroll 1
  for (int s = 0; s < 14; ++s) {
    WAIT_VM4();
    barrier_pinned();
    if (s & 1) comp(As1, Bs1); else comp(As0, Bs0);
    barrier_pinned();
    if (s & 1) stage((s + 2) * 64, As1, Bs1);
    else       stage((s + 2) * 64, As0, Bs0);
  }
  WAIT_VM4();
  barrier_pinned();
  comp(As0, Bs0);
  WAIT_VM0();
  barrier_pinned();
  comp(As1, Bs1);

  const int rgrp = (lane >> 4) * 4;
#pragma unroll
  for (int i = 0; i < 2; ++i) {
    const int nb = n0 + wr * 32 + i * 16 + rgrp;
#pragma unroll
    for (int j = 0; j < 2; ++j) {
      const int mcol = m0 + wc * 32 + j * 16 + (lane & 15);
      const float bb = bias[mcol];
#pragma unroll
      for (int r = 0; r < 4; ++r)
        out[(size_t)(nb + r) * HD + mcol] = acc[i][j][r] + bb;
    }
  }
}

extern "C" void kernel_launch(void* const* d_in, const int* in_sizes, int n_in,
                              void* d_out, int out_size, void* d_ws, size_t ws_size,
                              hipStream_t stream) {
  const float* q  = (const float*)d_in[0];
  const float* k  = (const float*)d_in[1];
  const float* v  = (const float*)d_in[2];
  const float* ab = (const float*)d_in[3];
  const float* Wq = (const float*)d_in[4];
  const float* bq = (const float*)d_in[5];
  const float* Wk = (const float*)d_in[6];
  const float* bk = (const float*)d_in[7];
  const float* Wv = (const float*)d_in[8];
  const float* bv = (const float*)d_in[9];
  const float* Wo = (const float*)d_in[10];
  const float* bo = (const float*)d_in[11];

  unsigned short* Wqb = (unsigned short*)d_ws;          // [HD][HD] bf16
  unsigned short* Wkb = Wqb + (size_t)HD * HD;
  unsigned short* Wvb = Wkb + (size_t)HD * HD;
  unsigned short* Wob = Wvb + (size_t)HD * HD;
  unsigned short* Qh  = Wob + (size_t)HD * HD;          // [NT][HD] bf16 (pre-scaled)
  unsigned short* Kh  = Qh + (size_t)NT * HD;           // [NT][HD]
  unsigned short* Vt  = Kh + (size_t)NT * HD;           // [HD][NT] (transposed)
  unsigned short* ctx = Vt + (size_t)NT * HD;           // [NT][HD]

  cvt_bf16<<<dim3(512, 4), 256, 0, stream>>>(Wq, Wk, Wv, Wo, Wqb, Wkb, Wvb, Wob);
  proj_gemm<<<dim3(768), 256, 0, stream>>>(
      q, k, v, Wqb, Wkb, Wvb, bq, bk, bv, Qh, Kh, Vt);
  attn_kernel<<<dim3(512), 256, 0, stream>>>(Qh, Kh, Vt, ab, ctx);
  out_gemm<<<dim3(512), 256, 0, stream>>>(ctx, Wob, bo, (float*)d_out);
}

// Round 10
// 119.640 us; speedup vs baseline: 1.0065x; 1.0065x over previous
//
#include <hip/hip_runtime.h>
#include <type_traits>
#include <utility>

#define NT 2048   // tokens
#define HD 1024   // hidden
#define NHEAD 16
#define DHEAD 64
#define LOG2E 1.44269504f

typedef float f32x4 __attribute__((ext_vector_type(4)));
typedef __bf16 b16x8 __attribute__((ext_vector_type(8)));
typedef short s16x8 __attribute__((ext_vector_type(8)));
typedef unsigned short u16x8 __attribute__((ext_vector_type(8)));
typedef unsigned short u16x4 __attribute__((ext_vector_type(4)));

// ---- MFMA builtin signature dispatch (bf16-vector vs short-vector toolchains) ----
template <typename V, typename = void>
struct mfma_takes : std::false_type {};
template <typename V>
struct mfma_takes<V, std::void_t<decltype(__builtin_amdgcn_mfma_f32_16x16x32_bf16(
                         std::declval<V>(), std::declval<V>(), std::declval<f32x4>(), 0, 0, 0))>>
    : std::true_type {};

template <typename V>
__device__ __forceinline__ f32x4 mfma_impl(V a, V b, f32x4 c) {
  return __builtin_amdgcn_mfma_f32_16x16x32_bf16(a, b, c, 0, 0, 0);
}

__device__ __forceinline__ f32x4 mfma_bf16(u16x8 a, u16x8 b, f32x4 c) {
  using V = typename std::conditional<mfma_takes<b16x8>::value, b16x8, s16x8>::type;
  return mfma_impl<V>(__builtin_bit_cast(V, a), __builtin_bit_cast(V, b), c);
}

__device__ __forceinline__ unsigned short f2bf(float f) {
  unsigned int u = __builtin_bit_cast(unsigned int, f);
  return (unsigned short)((u + 0x7FFFu + ((u >> 16) & 1u)) >> 16);
}

// async global->LDS, 16B per lane
__device__ __forceinline__ void gload16(const unsigned short* g, unsigned short* l) {
  __builtin_amdgcn_global_load_lds(
      (__attribute__((address_space(1))) void*)(void*)(g),
      (__attribute__((address_space(3))) void*)(void*)(l), 16, 0, 0);
}

// raw barrier pinned against compile-time motion of LDS/VMEM ops
__device__ __forceinline__ void barrier_pinned() {
  __builtin_amdgcn_sched_barrier(0);
  __builtin_amdgcn_s_barrier();
  __builtin_amdgcn_sched_barrier(0);
}
#define WAIT_VM32() asm volatile("s_waitcnt vmcnt(32)" ::: "memory")
#define WAIT_VM8() asm volatile("s_waitcnt vmcnt(8)" ::: "memory")
#define WAIT_VM4() asm volatile("s_waitcnt vmcnt(4)" ::: "memory")
#define WAIT_VM0() asm volatile("s_waitcnt vmcnt(0)" ::: "memory")
#define WAIT_LGKM0() asm volatile("s_waitcnt lgkmcnt(0)" ::: "memory")

// =====================================================================
// Kernel 0: fp32 -> bf16 conversion of the 4 weight matrices only
// (q/k/v conversion is fused into proj_gemm's A-staging).
// grid = (512, 4); each seg is HD*HD.
// =====================================================================
__global__ __launch_bounds__(256) void cvt_bf16(
    const float* __restrict__ s0, const float* __restrict__ s1, const float* __restrict__ s2,
    const float* __restrict__ s3,
    unsigned short* __restrict__ d0, unsigned short* __restrict__ d1,
    unsigned short* __restrict__ d2, unsigned short* __restrict__ d3) {
  const int seg = blockIdx.y;
  const float* s;
  unsigned short* d;
  switch (seg) {
    case 0: s = s0; d = d0; break;
    case 1: s = s1; d = d1; break;
    case 2: s = s2; d = d2; break;
    default: s = s3; d = d3; break;
  }
  const int i = blockIdx.x * 2048 + threadIdx.x * 8;
  f32x4 f0 = *reinterpret_cast<const f32x4*>(&s[i]);
  f32x4 f1 = *reinterpret_cast<const f32x4*>(&s[i + 4]);
  u16x8 o;
#pragma unroll
  for (int e = 0; e < 4; ++e) { o[e] = f2bf(f0[e]); o[e + 4] = f2bf(f1[e]); }
  *reinterpret_cast<u16x8*>(&d[i]) = o;
}

// =====================================================================
// Kernel 1: fused QKV projection with inline fp32->bf16 A-conversion.
// 1D grid 768: L = m*96 + z*32 + n (L%8 = n%8 -> A-panel shares an XCD).
// A (q/k/v) fp32: reg-loaded, converted, ds_written. B (weights) bf16 via
// global_load_lds. Ledger rule: finishA(s+1) BEFORE issueA(s+2) — areg is
// a single register set, consume before overwrite (R8 bug).
// z=0: Q scaled by 0.125*log2e row-major; z=1: K row-major; z=2: V transposed.
// =====================================================================
__global__ __launch_bounds__(256) void proj_gemm(
    const float* __restrict__ qf32, const float* __restrict__ kf32,
    const float* __restrict__ vf32,
    const unsigned short* __restrict__ Wqb, const unsigned short* __restrict__ Wkb,
    const unsigned short* __restrict__ Wvb,
    const float* __restrict__ bq, const float* __restrict__ bk, const float* __restrict__ bv,
    unsigned short* __restrict__ Qh, unsigned short* __restrict__ Kh,
    unsigned short* __restrict__ Vt) {
  const int L = blockIdx.x;
  const int m = L / 96;
  const int c = L % 96;
  const int z = c / 32;
  const int n = c % 32;
  const int n0 = n * 64, m0 = m * 128;

  const float* A = (z == 0) ? qf32 : (z == 1) ? kf32 : vf32;
  const unsigned short* B = (z == 0) ? Wqb : (z == 1) ? Wkb : Wvb;
  const float* bias = (z == 0) ? bq : (z == 1) ? bk : bv;

  __shared__ unsigned short As0[64 * 64], As1[64 * 64];
  __shared__ unsigned short Bs0[128 * 64], Bs1[128 * 64];

  const int tid = threadIdx.x;
  const int lane = tid & 63;
  const int wr = (tid >> 6) >> 1, wc = (tid >> 6) & 1;
  const int srow = tid >> 3;                              // 0..31
  const int schk = (tid & 7) ^ (srow & 7);                // swizzled chunk idx
  const int scol = schk << 3;                             // element offset

  f32x4 areg[4];  // in-flight fp32 A data (2 chunks x 2 f32x4)

  auto issueA = [&](int kt) {
#pragma unroll
    for (int p = 0; p < 2; ++p) {
      const float* src = &A[(size_t)(n0 + p * 32 + srow) * HD + kt + scol];
      areg[p * 2 + 0] = *reinterpret_cast<const f32x4*>(src);
      areg[p * 2 + 1] = *reinterpret_cast<const f32x4*>(src + 4);
    }
  };
  auto finishA = [&](unsigned short* as) {
#pragma unroll
    for (int p = 0; p < 2; ++p) {
      u16x8 o;
#pragma unroll
      for (int e = 0; e < 4; ++e) {
        o[e] = f2bf(areg[p * 2 + 0][e]);
        o[e + 4] = f2bf(areg[p * 2 + 1][e]);
      }
      *reinterpret_cast<u16x8*>(&as[p * 2048 + tid * 8]) = o;
    }
  };
  auto issueB = [&](int kt, unsigned short* bs) {
#pragma unroll
    for (int p = 0; p < 4; ++p)
      gload16(&B[(size_t)(m0 + p * 32 + srow) * HD + kt + scol], bs + p * 2048 + tid * 8);
  };
  f32x4 acc[2][4] = {};
  auto comp = [&](const unsigned short* as, const unsigned short* bs) {
#pragma unroll
    for (int ks = 0; ks < 2; ++ks) {
      const int q = ks * 4 + (lane >> 4);  // 16B-chunk index 0..7
      u16x8 a[2], b[4];
#pragma unroll
      for (int i = 0; i < 2; ++i) {
        const int row = wr * 32 + i * 16 + (lane & 15);
        a[i] = *reinterpret_cast<const u16x8*>(&as[row * 64 + ((q ^ (row & 7)) << 3)]);
      }
#pragma unroll
      for (int j = 0; j < 4; ++j) {
        const int row = wc * 64 + j * 16 + (lane & 15);
        b[j] = *reinterpret_cast<const u16x8*>(&bs[row * 64 + ((q ^ (row & 7)) << 3)]);
      }
#pragma unroll
      for (int i = 0; i < 2; ++i)
#pragma unroll
        for (int j = 0; j < 4; ++j)
          acc[i][j] = mfma_bf16(a[i], b[j], acc[i][j]);
    }
  };

  // ---- prologue (issue order: A0, B0, A1, B1) ----
  issueA(0);               // outst: A0 (4)
  issueB(0, Bs0);          // outst: A0,B0 (8)
  WAIT_VM4();              // A0 done (B0 in flight)
  finishA(As0);            // A0 -> As0 (areg free)
  issueA(64);              // outst: B0,A1 (8)
  issueB(64, Bs1);         // outst: B0,A1,B1 (12)

#pragma unroll 1
  for (int s = 0; s < 14; ++s) {
    WAIT_VM8();            // B(s) gload_lds complete; outst: A(s+1),B(s+1) (8)
    WAIT_LGKM0();          // this wave's A(s) ds_writes complete
    barrier_pinned();      // all waves' stage-s data visible
    if (s & 1) comp(As1, Bs1); else comp(As0, Bs0);
    barrier_pinned();      // all waves done reading buffers (s&1)
    WAIT_VM4();            // A(s+1) reg-loads complete; outst: B(s+1) (4)
    finishA((s & 1) ? As0 : As1);  // A(s+1) -> buf[(s+1)&1]  (consume areg BEFORE reissue)
    issueA((s + 2) * 64);          // outst: B(s+1),A(s+2) (8)
    issueB((s + 2) * 64, (s & 1) ? Bs1 : Bs0);  // outst: B(s+1),A(s+2),B(s+2) (12)
  }
  // epilogue: outst = B(14),A(15),B(15)
  WAIT_VM8();              // B(14) done
  WAIT_LGKM0();
  barrier_pinned();
  comp(As0, Bs0);          // stage 14 (buf 0)
  barrier_pinned();
  WAIT_VM4();              // A(15) done (B(15) in flight)
  finishA(As1);
  WAIT_VM0();              // B(15) done
  WAIT_LGKM0();
  barrier_pinned();
  comp(As1, Bs1);

  const int rgrp = (lane >> 4) * 4;
  const float scale = (z == 0) ? 0.125f * LOG2E : 1.0f;
#pragma unroll
  for (int i = 0; i < 2; ++i) {
    const int nb = n0 + wr * 32 + i * 16 + rgrp;
#pragma unroll
    for (int j = 0; j < 4; ++j) {
      const int mcol = m0 + wc * 64 + j * 16 + (lane & 15);
      const float bb = bias[mcol];
      if (z == 2) {
        u16x4 pk;
#pragma unroll
        for (int r = 0; r < 4; ++r) pk[r] = f2bf(acc[i][j][r] + bb);
        *reinterpret_cast<u16x4*>(&Vt[(size_t)mcol * NT + nb]) = pk;  // transposed store
      } else {
        unsigned short* dst = (z == 0) ? Qh : Kh;
#pragma unroll
        for (int r = 0; r < 4; ++r)
          dst[(size_t)(nb + r) * HD + mcol] = f2bf((acc[i][j][r] + bb) * scale);
      }
    }
  }
}

// =====================================================================
// Kernel 2: flash attention with additive bias (log2-domain softmax).
// 1D grid 512: xcd = id&7 owns heads {2*xcd, 2*xcd+1} (K/V L2 locality).
// 256 threads = 4 waves x 16 q-rows. K/V double-buffered via
// global_load_lds; end-of-iter sync is a COUNTED vmcnt(32): the 8 K/V
// stage loads are the oldest outstanding, so they retire while the 32
// bias loads (issued after them) stay in flight across the barrier and
// land under the next tile's QK^T (T4: never drain to 0 in-loop).
// 80KB LDS -> 2 blocks/CU.
// =====================================================================
__global__ __launch_bounds__(256, 2) void attn_kernel(
    const unsigned short* __restrict__ Qh, const unsigned short* __restrict__ Kh,
    const unsigned short* __restrict__ Vt, const float* __restrict__ bias,
    unsigned short* __restrict__ ctx) {
  const int id = blockIdx.x;
  const int xcd = id & 7, slot = id >> 3;
  const int h = xcd * 2 + (slot >> 5);
  const int q0 = (slot & 31) * 64;
  const int tid = threadIdx.x;
  const int lane = tid & 63;
  const int wave = tid >> 6;

  __shared__ unsigned short Ks0[128 * 64], Ks1[128 * 64];   // 16KB each
  __shared__ unsigned short Vs0[64 * 128], Vs1[64 * 128];   // 16KB each
  __shared__ unsigned short Ps[4 * 16 * 128];               // 16KB  => 80KB total

  u16x8 qf[2];
  {
    const int qrow = q0 + wave * 16 + (lane & 15);
    const int db = (lane >> 4) * 8;
    qf[0] = *reinterpret_cast<const u16x8*>(&Qh[(size_t)qrow * HD + h * DHEAD + db]);
    qf[1] = *reinterpret_cast<const u16x8*>(&Qh[(size_t)qrow * HD + h * DHEAD + 32 + db]);
  }

  f32x4 oacc[4] = {};
  float mrun[4], lrun[4];
#pragma unroll
  for (int r = 0; r < 4; ++r) { mrun[r] = -3.0e38f; lrun[r] = 0.f; }

  const float* bias_h = bias + (size_t)h * NT * NT;
  const int qlrow = q0 + wave * 16 + (lane >> 4) * 4;  // + r
  const float* bias_l = bias_h + (size_t)qlrow * NT + (lane & 15);

  const unsigned short* Kbase = Kh + h * DHEAD;
  const unsigned short* Vbase = Vt + (size_t)h * DHEAD * NT;

  const int krow = tid >> 3;
  const int kchk = tid & 7;
  const int vrow = tid >> 4;
  const int vchk = tid & 15;

  auto stage = [&](int t, unsigned short* ks, unsigned short* vs) {
    const int kt = t * 128;
#pragma unroll
    for (int p = 0; p < 4; ++p) {
      const int r = p * 32 + krow;
      gload16(&Kbase[(size_t)(kt + r) * HD + ((kchk ^ (r & 7)) << 3)], ks + p * 2048 + tid * 8);
    }
#pragma unroll
    for (int p = 0; p < 4; ++p) {
      const int r = p * 16 + vrow;
      gload16(&Vbase[(size_t)r * NT + kt + ((vchk ^ (r & 7)) << 3)], vs + p * 2048 + tid * 8);
    }
  };

  float br[8][4];
#pragma unroll
  for (int j = 0; j < 8; ++j)
#pragma unroll
    for (int r = 0; r < 4; ++r) br[j][r] = bias_l[(size_t)r * NT + j * 16];
  stage(0, Ks0, Vs0);
  WAIT_VM0();
  barrier_pinned();

  unsigned short* const psw = Ps + wave * 2048;

#pragma unroll 1
  for (int t = 0; t < NT / 128; ++t) {
    const bool more = (t + 1 < NT / 128);
    const unsigned short* ks = (t & 1) ? Ks1 : Ks0;
    const unsigned short* vs = (t & 1) ? Vs1 : Vs0;

    if (more) stage(t + 1, (t & 1) ? Ks0 : Ks1, (t & 1) ? Vs0 : Vs1);

    // ---- QK^T (Q pre-scaled by 0.125*log2e) ----
    f32x4 s[8] = {};
#pragma unroll
    for (int kss = 0; kss < 2; ++kss) {
      const int q = kss * 4 + (lane >> 4);
#pragma unroll
      for (int j = 0; j < 8; ++j) {
        const int row = j * 16 + (lane & 15);
        u16x8 kf = *reinterpret_cast<const u16x8*>(&ks[row * 64 + ((q ^ (row & 7)) << 3)]);
        s[j] = mfma_bf16(qf[kss], kf, s[j]);
      }
    }
#pragma unroll
    for (int j = 0; j < 8; ++j)
#pragma unroll
      for (int r = 0; r < 4; ++r) s[j][r] = fmaf(br[j][r], LOG2E, s[j][r]);

    // ---- issue bias tile t+1 (AFTER the stage loads -> stage is oldest) ----
    if (more) {
      const float* bp = bias_l + (size_t)(t + 1) * 128;
#pragma unroll
      for (int j = 0; j < 8; ++j)
#pragma unroll
        for (int r = 0; r < 4; ++r) br[j][r] = bp[(size_t)r * NT + j * 16];
    }

    // ---- online softmax (log2 domain) ----
    float mnew[4];
#pragma unroll
    for (int r = 0; r < 4; ++r) {
      float mx = s[0][r];
#pragma unroll
      for (int j = 1; j < 8; ++j) mx = fmaxf(mx, s[j][r]);
      mx = fmaxf(mx, __shfl_xor(mx, 1));
      mx = fmaxf(mx, __shfl_xor(mx, 2));
      mx = fmaxf(mx, __shfl_xor(mx, 4));
      mx = fmaxf(mx, __shfl_xor(mx, 8));
      mnew[r] = fmaxf(mrun[r], mx);
    }
#pragma unroll
    for (int r = 0; r < 4; ++r) {
      const float corr = exp2f(mrun[r] - mnew[r]);
      lrun[r] *= corr;
#pragma unroll
      for (int nd = 0; nd < 4; ++nd) oacc[nd][r] *= corr;
      mrun[r] = mnew[r];
    }
    float psum[4] = {0.f, 0.f, 0.f, 0.f};
#pragma unroll
    for (int j = 0; j < 8; ++j) {
      const int chkbase = j * 2 + ((lane >> 3) & 1);
      const int cofs = lane & 7;
#pragma unroll
      for (int r = 0; r < 4; ++r) {
        const int row = (lane >> 4) * 4 + r;
        const float p = exp2f(s[j][r] - mrun[r]);
        psum[r] += p;
        psw[row * 128 + ((chkbase ^ (row & 7)) << 3) + cofs] = f2bf(p);
      }
    }
#pragma unroll
    for (int r = 0; r < 4; ++r) {
      float tsum = psum[r];
      tsum += __shfl_xor(tsum, 1);
      tsum += __shfl_xor(tsum, 2);
      tsum += __shfl_xor(tsum, 4);
      tsum += __shfl_xor(tsum, 8);
      lrun[r] += tsum;
    }

    // ---- PV ----
#pragma unroll
    for (int kk = 0; kk < 4; ++kk) {
      const int q = kk * 4 + (lane >> 4);
      const int prow = lane & 15;
      u16x8 pa = *reinterpret_cast<const u16x8*>(&psw[prow * 128 + ((q ^ (prow & 7)) << 3)]);
#pragma unroll
      for (int nd = 0; nd < 4; ++nd) {
        const int vr = nd * 16 + (lane & 15);
        u16x8 vb = *reinterpret_cast<const u16x8*>(&vs[vr * 128 + ((q ^ (vr & 7)) << 3)]);
        oacc[nd] = mfma_bf16(pa, vb, oacc[nd]);
      }
    }

    // ---- counted sync: retire the 8 stage loads (oldest); the 32 bias
    //      loads stay in flight across the barrier ----
    WAIT_VM32();
    barrier_pinned();
  }

#pragma unroll
  for (int nd = 0; nd < 4; ++nd) {
#pragma unroll
    for (int r = 0; r < 4; ++r) {
      const float val = oacc[nd][r] / lrun[r];
      ctx[(size_t)(qlrow + r) * HD + h * DHEAD + nd * 16 + (lane & 15)] = f2bf(val);
    }
  }
}

// =====================================================================
// Kernel 3: output projection, fp32 out. 64x64 tiles, 1D grid 512:
// L = m*32 + n (L%8 = n%8 XCD grouping). 2 blocks/CU. vmcnt(4) pipeline.
// =====================================================================
__global__ __launch_bounds__(256) void out_gemm(
    const unsigned short* __restrict__ Ain, const unsigned short* __restrict__ Wob,
    const float* __restrict__ bias, float* __restrict__ out) {
  const int L = blockIdx.x;
  const int m = L / 32;
  const int n = L % 32;
  const int n0 = n * 64, m0 = m * 64;

  __shared__ unsigned short As0[64 * 64], As1[64 * 64];
  __shared__ unsigned short Bs0[64 * 64], Bs1[64 * 64];

  const int tid = threadIdx.x;
  const int lane = tid & 63;
  const int wr = (tid >> 6) >> 1, wc = (tid >> 6) & 1;
  const int srow = tid >> 3;                              // 0..31
  const int scol = (((tid & 7) ^ (srow & 7)) << 3);       // swizzled source chunk

  auto stage = [&](int kt, unsigned short* as, unsigned short* bs) {
#pragma unroll
    for (int p = 0; p < 2; ++p)
      gload16(&Ain[(size_t)(n0 + p * 32 + srow) * HD + kt + scol], as + p * 2048 + tid * 8);
#pragma unroll
    for (int p = 0; p < 2; ++p)
      gload16(&Wob[(size_t)(m0 + p * 32 + srow) * HD + kt + scol], bs + p * 2048 + tid * 8);
  };
  f32x4 acc[2][2] = {};
  auto comp = [&](const unsigned short* as, const unsigned short* bs) {
#pragma unroll
    for (int ks = 0; ks < 2; ++ks) {
      const int q = ks * 4 + (lane >> 4);
      u16x8 a[2], b[2];
#pragma unroll
      for (int i = 0; i < 2; ++i) {
        const int row = wr * 32 + i * 16 + (lane & 15);
        a[i] = *reinterpret_cast<const u16x8*>(&as[row * 64 + ((q ^ (row & 7)) << 3)]);
      }
#pragma unroll
      for (int j = 0; j < 2; ++j) {
        const int row = wc * 32 + j * 16 + (lane & 15);
        b[j] = *reinterpret_cast<const u16x8*>(&bs[row * 64 + ((q ^ (row & 7)) << 3)]);
      }
#pragma unroll
      for (int i = 0; i < 2; ++i)
#pragma unroll
        for (int j = 0; j < 2; ++j)
          acc[i][j] = mfma_bf16(a[i], b[j], acc[i][j]);
    }
  };

  stage(0, As0, Bs0);
  stage(64, As1, Bs1);
#pragma unroll 1
  for (int s = 0; s < 14; ++s) {
    WAIT_VM4();
    barrier_pinned();
    if (s & 1) comp(As1, Bs1); else comp(As0, Bs0);
    barrier_pinned();
    if (s & 1) stage((s + 2) * 64, As1, Bs1);
    else       stage((s + 2) * 64, As0, Bs0);
  }
  WAIT_VM4();
  barrier_pinned();
  comp(As0, Bs0);
  WAIT_VM0();
  barrier_pinned();
  comp(As1, Bs1);

  const int rgrp = (lane >> 4) * 4;
#pragma unroll
  for (int i = 0; i < 2; ++i) {
    const int nb = n0 + wr * 32 + i * 16 + rgrp;
#pragma unroll
    for (int j = 0; j < 2; ++j) {
      const int mcol = m0 + wc * 32 + j * 16 + (lane & 15);
      const float bb = bias[mcol];
#pragma unroll
      for (int r = 0; r < 4; ++r)
        out[(size_t)(nb + r) * HD + mcol] = acc[i][j][r] + bb;
    }
  }
}

extern "C" void kernel_launch(void* const* d_in, const int* in_sizes, int n_in,
                              void* d_out, int out_size, void* d_ws, size_t ws_size,
                              hipStream_t stream) {
  const float* q  = (const float*)d_in[0];
  const float* k  = (const float*)d_in[1];
  const float* v  = (const float*)d_in[2];
  const float* ab = (const float*)d_in[3];
  const float* Wq = (const float*)d_in[4];
  const float* bq = (const float*)d_in[5];
  const float* Wk = (const float*)d_in[6];
  const float* bk = (const float*)d_in[7];
  const float* Wv = (const float*)d_in[8];
  const float* bv = (const float*)d_in[9];
  const float* Wo = (const float*)d_in[10];
  const float* bo = (const float*)d_in[11];

  unsigned short* Wqb = (unsigned short*)d_ws;          // [HD][HD] bf16
  unsigned short* Wkb = Wqb + (size_t)HD * HD;
  unsigned short* Wvb = Wkb + (size_t)HD * HD;
  unsigned short* Wob = Wvb + (size_t)HD * HD;
  unsigned short* Qh  = Wob + (size_t)HD * HD;          // [NT][HD] bf16 (pre-scaled)
  unsigned short* Kh  = Qh + (size_t)NT * HD;           // [NT][HD]
  unsigned short* Vt  = Kh + (size_t)NT * HD;           // [HD][NT] (transposed)
  unsigned short* ctx = Vt + (size_t)NT * HD;           // [NT][HD]

  cvt_bf16<<<dim3(512, 4), 256, 0, stream>>>(Wq, Wk, Wv, Wo, Wqb, Wkb, Wvb, Wob);
  proj_gemm<<<dim3(768), 256, 0, stream>>>(
      q, k, v, Wqb, Wkb, Wvb, bq, bk, bv, Qh, Kh, Vt);
  attn_kernel<<<dim3(512), 256, 0, stream>>>(Qh, Kh, Vt, ab, ctx);
  out_gemm<<<dim3(512), 256, 0, stream>>>(ctx, Wob, bo, (float*)d_out);
}

// Round 11
// 118.109 us; speedup vs baseline: 1.0195x; 1.0130x over previous
//
#include <hip/hip_runtime.h>
#include <type_traits>
#include <utility>

#define NT 2048   // tokens
#define HD 1024   // hidden
#define NHEAD 16
#define DHEAD 64
#define LOG2E 1.44269504f

typedef float f32x4 __attribute__((ext_vector_type(4)));
typedef __bf16 b16x8 __attribute__((ext_vector_type(8)));
typedef short s16x8 __attribute__((ext_vector_type(8)));
typedef unsigned short u16x8 __attribute__((ext_vector_type(8)));
typedef unsigned short u16x4 __attribute__((ext_vector_type(4)));

// ---- MFMA builtin signature dispatch (bf16-vector vs short-vector toolchains) ----
template <typename V, typename = void>
struct mfma_takes : std::false_type {};
template <typename V>
struct mfma_takes<V, std::void_t<decltype(__builtin_amdgcn_mfma_f32_16x16x32_bf16(
                         std::declval<V>(), std::declval<V>(), std::declval<f32x4>(), 0, 0, 0))>>
    : std::true_type {};

template <typename V>
__device__ __forceinline__ f32x4 mfma_impl(V a, V b, f32x4 c) {
  return __builtin_amdgcn_mfma_f32_16x16x32_bf16(a, b, c, 0, 0, 0);
}

__device__ __forceinline__ f32x4 mfma_bf16(u16x8 a, u16x8 b, f32x4 c) {
  using V = typename std::conditional<mfma_takes<b16x8>::value, b16x8, s16x8>::type;
  return mfma_impl<V>(__builtin_bit_cast(V, a), __builtin_bit_cast(V, b), c);
}

__device__ __forceinline__ unsigned short f2bf(float f) {
  unsigned int u = __builtin_bit_cast(unsigned int, f);
  return (unsigned short)((u + 0x7FFFu + ((u >> 16) & 1u)) >> 16);
}

// async global->LDS, 16B per lane
__device__ __forceinline__ void gload16(const unsigned short* g, unsigned short* l) {
  __builtin_amdgcn_global_load_lds(
      (__attribute__((address_space(1))) void*)(void*)(g),
      (__attribute__((address_space(3))) void*)(void*)(l), 16, 0, 0);
}

// raw barrier pinned against compile-time motion of LDS/VMEM ops
__device__ __forceinline__ void barrier_pinned() {
  __builtin_amdgcn_sched_barrier(0);
  __builtin_amdgcn_s_barrier();
  __builtin_amdgcn_sched_barrier(0);
}
#define WAIT_VM32() asm volatile("s_waitcnt vmcnt(32)" ::: "memory")
#define WAIT_VM6() asm volatile("s_waitcnt vmcnt(6)" ::: "memory")
#define WAIT_VM4() asm volatile("s_waitcnt vmcnt(4)" ::: "memory")
#define WAIT_VM0() asm volatile("s_waitcnt vmcnt(0)" ::: "memory")
#define WAIT_LGKM0() asm volatile("s_waitcnt lgkmcnt(0)" ::: "memory")

// =====================================================================
// Kernel 0: fp32 -> bf16 conversion of q,k,v and the 4 weight matrices.
// grid = (512, 7); segs 0..2 are [NT*HD] (loop twice), 3..6 are [HD*HD].
// =====================================================================
__global__ __launch_bounds__(256) void cvt_bf16(
    const float* __restrict__ s0, const float* __restrict__ s1, const float* __restrict__ s2,
    const float* __restrict__ s3, const float* __restrict__ s4, const float* __restrict__ s5,
    const float* __restrict__ s6,
    unsigned short* __restrict__ d0, unsigned short* __restrict__ d1, unsigned short* __restrict__ d2,
    unsigned short* __restrict__ d3, unsigned short* __restrict__ d4, unsigned short* __restrict__ d5,
    unsigned short* __restrict__ d6) {
  const int seg = blockIdx.y;
  const float* s;
  unsigned short* d;
  switch (seg) {
    case 0: s = s0; d = d0; break;
    case 1: s = s1; d = d1; break;
    case 2: s = s2; d = d2; break;
    case 3: s = s3; d = d3; break;
    case 4: s = s4; d = d4; break;
    case 5: s = s5; d = d5; break;
    default: s = s6; d = d6; break;
  }
  const int n = (seg < 3) ? NT * HD : HD * HD;
  for (int i = blockIdx.x * 2048 + threadIdx.x * 8; i < n; i += gridDim.x * 2048) {
    f32x4 f0 = *reinterpret_cast<const f32x4*>(&s[i]);
    f32x4 f1 = *reinterpret_cast<const f32x4*>(&s[i + 4]);
    u16x8 o;
#pragma unroll
    for (int e = 0; e < 4; ++e) { o[e] = f2bf(f0[e]); o[e + 4] = f2bf(f1[e]); }
    *reinterpret_cast<u16x8*>(&d[i]) = o;
  }
}

// =====================================================================
// 64x128 GEMM mainloop: counted-vmcnt double-buffer pipeline with T2
// XOR-swizzled LDS (swizzle on the GLOBAL source; gload_lds dest linear).
// C[64 x 128] = A[n0:, :] . B[m0:, :]^T, bf16, K = HD. 4 waves (2x2).
// =====================================================================
__device__ __forceinline__ void gemm64x128(
    const unsigned short* __restrict__ A, const unsigned short* __restrict__ B,
    int n0, int m0,
    unsigned short* As0, unsigned short* As1,
    unsigned short* Bs0, unsigned short* Bs1, f32x4 acc[2][4]) {
  const int tid = threadIdx.x;
  const int lane = tid & 63;
  const int wr = (tid >> 6) >> 1, wc = (tid >> 6) & 1;
  const int srow = tid >> 3;                              // 0..31
  const int scol = (((tid & 7) ^ (srow & 7)) << 3);       // swizzled source chunk

  auto stage = [&](int kt, unsigned short* as, unsigned short* bs) {
#pragma unroll
    for (int p = 0; p < 2; ++p)
      gload16(&A[(size_t)(n0 + p * 32 + srow) * HD + kt + scol], as + p * 2048 + tid * 8);
#pragma unroll
    for (int p = 0; p < 4; ++p)
      gload16(&B[(size_t)(m0 + p * 32 + srow) * HD + kt + scol], bs + p * 2048 + tid * 8);
  };
  auto comp = [&](const unsigned short* as, const unsigned short* bs) {
#pragma unroll
    for (int ks = 0; ks < 2; ++ks) {
      const int q = ks * 4 + (lane >> 4);  // 16B-chunk index 0..7
      u16x8 a[2], b[4];
#pragma unroll
      for (int i = 0; i < 2; ++i) {
        const int row = wr * 32 + i * 16 + (lane & 15);
        a[i] = *reinterpret_cast<const u16x8*>(&as[row * 64 + ((q ^ (row & 7)) << 3)]);
      }
#pragma unroll
      for (int j = 0; j < 4; ++j) {
        const int row = wc * 64 + j * 16 + (lane & 15);
        b[j] = *reinterpret_cast<const u16x8*>(&bs[row * 64 + ((q ^ (row & 7)) << 3)]);
      }
#pragma unroll
      for (int i = 0; i < 2; ++i)
#pragma unroll
        for (int j = 0; j < 4; ++j)
          acc[i][j] = mfma_bf16(a[i], b[j], acc[i][j]);
    }
  };

  stage(0, As0, Bs0);
  stage(64, As1, Bs1);
#pragma unroll 1
  for (int s = 0; s < 14; ++s) {
    WAIT_VM6();          // oldest stage (s) complete; stage s+1 still in flight
    barrier_pinned();    // all waves' stage-s writes visible
    if (s & 1) comp(As1, Bs1); else comp(As0, Bs0);
    barrier_pinned();    // all waves done reading buffer (s&1)
    if (s & 1) stage((s + 2) * 64, As1, Bs1);
    else       stage((s + 2) * 64, As0, Bs0);
  }
  WAIT_VM6();
  barrier_pinned();
  comp(As0, Bs0);
  WAIT_VM0();
  barrier_pinned();
  comp(As1, Bs1);
}

// =====================================================================
// Kernel 1: fused QKV projection. 1D grid 768: L = m*96 + z*32 + n
// (L%8 = n%8 -> the 8 m-blocks of one (z,n) share an XCD/L2 A-panel).
// z=0: Q scaled by 0.125*log2e row-major; z=1: K row-major; z=2: V transposed.
// =====================================================================
__global__ __launch_bounds__(256) void proj_gemm(
    const unsigned short* __restrict__ qb, const unsigned short* __restrict__ kb,
    const unsigned short* __restrict__ vb,
    const unsigned short* __restrict__ Wqb, const unsigned short* __restrict__ Wkb,
    const unsigned short* __restrict__ Wvb,
    const float* __restrict__ bq, const float* __restrict__ bk, const float* __restrict__ bv,
    unsigned short* __restrict__ Qh, unsigned short* __restrict__ Kh,
    unsigned short* __restrict__ Vt) {
  const int L = blockIdx.x;
  const int m = L / 96;
  const int c = L % 96;
  const int z = c / 32;
  const int n = c % 32;
  const int n0 = n * 64, m0 = m * 128;

  const unsigned short* A = (z == 0) ? qb : (z == 1) ? kb : vb;
  const unsigned short* B = (z == 0) ? Wqb : (z == 1) ? Wkb : Wvb;
  const float* bias = (z == 0) ? bq : (z == 1) ? bk : bv;

  __shared__ unsigned short As0[64 * 64], As1[64 * 64];
  __shared__ unsigned short Bs0[128 * 64], Bs1[128 * 64];

  const int tid = threadIdx.x;
  const int lane = tid & 63;
  const int wr = (tid >> 6) >> 1, wc = (tid >> 6) & 1;

  f32x4 acc[2][4] = {};
  gemm64x128(A, B, n0, m0, As0, As1, Bs0, Bs1, acc);

  const int rgrp = (lane >> 4) * 4;
  const float scale = (z == 0) ? 0.125f * LOG2E : 1.0f;
#pragma unroll
  for (int i = 0; i < 2; ++i) {
    const int nb = n0 + wr * 32 + i * 16 + rgrp;
#pragma unroll
    for (int j = 0; j < 4; ++j) {
      const int mcol = m0 + wc * 64 + j * 16 + (lane & 15);
      const float bb = bias[mcol];
      if (z == 2) {
        u16x4 pk;
#pragma unroll
        for (int r = 0; r < 4; ++r) pk[r] = f2bf(acc[i][j][r] + bb);
        *reinterpret_cast<u16x4*>(&Vt[(size_t)mcol * NT + nb]) = pk;  // transposed store
      } else {
        unsigned short* dst = (z == 0) ? Qh : Kh;
#pragma unroll
        for (int r = 0; r < 4; ++r)
          dst[(size_t)(nb + r) * HD + mcol] = f2bf((acc[i][j][r] + bb) * scale);
      }
    }
  }
}

// =====================================================================
// Kernel 2: flash attention with additive bias (log2-domain softmax).
// 1D grid 512: xcd = id&7 owns heads {2*xcd, 2*xcd+1} (K/V L2 locality).
// 256 threads = 4 waves x 16 q-rows. K/V double-buffered via
// global_load_lds; end-of-iter sync is a COUNTED vmcnt(32): the 8 K/V
// stage loads are the oldest outstanding, so they retire while the 32
// bias loads stay in flight across the barrier. 80KB LDS -> 2 blocks/CU.
// =====================================================================
__global__ __launch_bounds__(256, 2) void attn_kernel(
    const unsigned short* __restrict__ Qh, const unsigned short* __restrict__ Kh,
    const unsigned short* __restrict__ Vt, const float* __restrict__ bias,
    unsigned short* __restrict__ ctx) {
  const int id = blockIdx.x;
  const int xcd = id & 7, slot = id >> 3;
  const int h = xcd * 2 + (slot >> 5);
  const int q0 = (slot & 31) * 64;
  const int tid = threadIdx.x;
  const int lane = tid & 63;
  const int wave = tid >> 6;

  __shared__ unsigned short Ks0[128 * 64], Ks1[128 * 64];   // 16KB each
  __shared__ unsigned short Vs0[64 * 128], Vs1[64 * 128];   // 16KB each
  __shared__ unsigned short Ps[4 * 16 * 128];               // 16KB  => 80KB total

  u16x8 qf[2];
  {
    const int qrow = q0 + wave * 16 + (lane & 15);
    const int db = (lane >> 4) * 8;
    qf[0] = *reinterpret_cast<const u16x8*>(&Qh[(size_t)qrow * HD + h * DHEAD + db]);
    qf[1] = *reinterpret_cast<const u16x8*>(&Qh[(size_t)qrow * HD + h * DHEAD + 32 + db]);
  }

  f32x4 oacc[4] = {};
  float mrun[4], lrun[4];
#pragma unroll
  for (int r = 0; r < 4; ++r) { mrun[r] = -3.0e38f; lrun[r] = 0.f; }

  const float* bias_h = bias + (size_t)h * NT * NT;
  const int qlrow = q0 + wave * 16 + (lane >> 4) * 4;  // + r
  const float* bias_l = bias_h + (size_t)qlrow * NT + (lane & 15);

  const unsigned short* Kbase = Kh + h * DHEAD;
  const unsigned short* Vbase = Vt + (size_t)h * DHEAD * NT;

  const int krow = tid >> 3;
  const int kchk = tid & 7;
  const int vrow = tid >> 4;
  const int vchk = tid & 15;

  auto stage = [&](int t, unsigned short* ks, unsigned short* vs) {
    const int kt = t * 128;
#pragma unroll
    for (int p = 0; p < 4; ++p) {
      const int r = p * 32 + krow;
      gload16(&Kbase[(size_t)(kt + r) * HD + ((kchk ^ (r & 7)) << 3)], ks + p * 2048 + tid * 8);
    }
#pragma unroll
    for (int p = 0; p < 4; ++p) {
      const int r = p * 16 + vrow;
      gload16(&Vbase[(size_t)r * NT + kt + ((vchk ^ (r & 7)) << 3)], vs + p * 2048 + tid * 8);
    }
  };

  float br[8][4];
#pragma unroll
  for (int j = 0; j < 8; ++j)
#pragma unroll
    for (int r = 0; r < 4; ++r) br[j][r] = bias_l[(size_t)r * NT + j * 16];
  stage(0, Ks0, Vs0);
  WAIT_VM0();
  barrier_pinned();

  unsigned short* const psw = Ps + wave * 2048;

#pragma unroll 1
  for (int t = 0; t < NT / 128; ++t) {
    const bool more = (t + 1 < NT / 128);
    const unsigned short* ks = (t & 1) ? Ks1 : Ks0;
    const unsigned short* vs = (t & 1) ? Vs1 : Vs0;

    if (more) stage(t + 1, (t & 1) ? Ks0 : Ks1, (t & 1) ? Vs0 : Vs1);

    // ---- QK^T (Q pre-scaled by 0.125*log2e) ----
    f32x4 s[8] = {};
#pragma unroll
    for (int kss = 0; kss < 2; ++kss) {
      const int q = kss * 4 + (lane >> 4);
#pragma unroll
      for (int j = 0; j < 8; ++j) {
        const int row = j * 16 + (lane & 15);
        u16x8 kf = *reinterpret_cast<const u16x8*>(&ks[row * 64 + ((q ^ (row & 7)) << 3)]);
        s[j] = mfma_bf16(qf[kss], kf, s[j]);
      }
    }
#pragma unroll
    for (int j = 0; j < 8; ++j)
#pragma unroll
      for (int r = 0; r < 4; ++r) s[j][r] = fmaf(br[j][r], LOG2E, s[j][r]);

    // ---- issue bias tile t+1 (AFTER the stage loads -> stage is oldest) ----
    if (more) {
      const float* bp = bias_l + (size_t)(t + 1) * 128;
#pragma unroll
      for (int j = 0; j < 8; ++j)
#pragma unroll
        for (int r = 0; r < 4; ++r) br[j][r] = bp[(size_t)r * NT + j * 16];
    }

    // ---- online softmax (log2 domain) ----
    float mnew[4];
#pragma unroll
    for (int r = 0; r < 4; ++r) {
      float mx = s[0][r];
#pragma unroll
      for (int j = 1; j < 8; ++j) mx = fmaxf(mx, s[j][r]);
      mx = fmaxf(mx, __shfl_xor(mx, 1));
      mx = fmaxf(mx, __shfl_xor(mx, 2));
      mx = fmaxf(mx, __shfl_xor(mx, 4));
      mx = fmaxf(mx, __shfl_xor(mx, 8));
      mnew[r] = fmaxf(mrun[r], mx);
    }
#pragma unroll
    for (int r = 0; r < 4; ++r) {
      const float corr = exp2f(mrun[r] - mnew[r]);
      lrun[r] *= corr;
#pragma unroll
      for (int nd = 0; nd < 4; ++nd) oacc[nd][r] *= corr;
      mrun[r] = mnew[r];
    }
    float psum[4] = {0.f, 0.f, 0.f, 0.f};
#pragma unroll
    for (int j = 0; j < 8; ++j) {
      const int chkbase = j * 2 + ((lane >> 3) & 1);
      const int cofs = lane & 7;
#pragma unroll
      for (int r = 0; r < 4; ++r) {
        const int row = (lane >> 4) * 4 + r;
        const float p = exp2f(s[j][r] - mrun[r]);
        psum[r] += p;
        psw[row * 128 + ((chkbase ^ (row & 7)) << 3) + cofs] = f2bf(p);
      }
    }
#pragma unroll
    for (int r = 0; r < 4; ++r) {
      float tsum = psum[r];
      tsum += __shfl_xor(tsum, 1);
      tsum += __shfl_xor(tsum, 2);
      tsum += __shfl_xor(tsum, 4);
      tsum += __shfl_xor(tsum, 8);
      lrun[r] += tsum;
    }

    // ---- PV ----
#pragma unroll
    for (int kk = 0; kk < 4; ++kk) {
      const int q = kk * 4 + (lane >> 4);
      const int prow = lane & 15;
      u16x8 pa = *reinterpret_cast<const u16x8*>(&psw[prow * 128 + ((q ^ (prow & 7)) << 3)]);
#pragma unroll
      for (int nd = 0; nd < 4; ++nd) {
        const int vr = nd * 16 + (lane & 15);
        u16x8 vb = *reinterpret_cast<const u16x8*>(&vs[vr * 128 + ((q ^ (vr & 7)) << 3)]);
        oacc[nd] = mfma_bf16(pa, vb, oacc[nd]);
      }
    }

    // ---- counted sync: retire the 8 stage loads (oldest); bias stays in flight
    WAIT_VM32();
    barrier_pinned();
  }

#pragma unroll
  for (int nd = 0; nd < 4; ++nd) {
#pragma unroll
    for (int r = 0; r < 4; ++r) {
      const float val = oacc[nd][r] / lrun[r];
      ctx[(size_t)(qlrow + r) * HD + h * DHEAD + nd * 16 + (lane & 15)] = f2bf(val);
    }
  }
}

// =====================================================================
// Kernel 3: output projection, fp32 out. 64x64 tiles, 1D grid 512:
// L = m*32 + n (L%8 = n%8 XCD grouping). 2 blocks/CU. vmcnt(4) pipeline.
// =====================================================================
__global__ __launch_bounds__(256) void out_gemm(
    const unsigned short* __restrict__ Ain, const unsigned short* __restrict__ Wob,
    const float* __restrict__ bias, float* __restrict__ out) {
  const int L = blockIdx.x;
  const int m = L / 32;
  const int n = L % 32;
  const int n0 = n * 64, m0 = m * 64;

  __shared__ unsigned short As0[64 * 64], As1[64 * 64];
  __shared__ unsigned short Bs0[64 * 64], Bs1[64 * 64];

  const int tid = threadIdx.x;
  const int lane = tid & 63;
  const int wr = (tid >> 6) >> 1, wc = (tid >> 6) & 1;
  const int srow = tid >> 3;                              // 0..31
  const int scol = (((tid & 7) ^ (srow & 7)) << 3);       // swizzled source chunk

  auto stage = [&](int kt, unsigned short* as, unsigned short* bs) {
#pragma unroll
    for (int p = 0; p < 2; ++p)
      gload16(&Ain[(size_t)(n0 + p * 32 + srow) * HD + kt + scol], as + p * 2048 + tid * 8);
#pragma unroll
    for (int p = 0; p < 2; ++p)
      gload16(&Wob[(size_t)(m0 + p * 32 + srow) * HD + kt + scol], bs + p * 2048 + tid * 8);
  };
  f32x4 acc[2][2] = {};
  auto comp = [&](const unsigned short* as, const unsigned short* bs) {
#pragma unroll
    for (int ks = 0; ks < 2; ++ks) {
      const int q = ks * 4 + (lane >> 4);
      u16x8 a[2], b[2];
#pragma unroll
      for (int i = 0; i < 2; ++i) {
        const int row = wr * 32 + i * 16 + (lane & 15);
        a[i] = *reinterpret_cast<const u16x8*>(&as[row * 64 + ((q ^ (row & 7)) << 3)]);
      }
#pragma unroll
      for (int j = 0; j < 2; ++j) {
        const int row = wc * 32 + j * 16 + (lane & 15);
        b[j] = *reinterpret_cast<const u16x8*>(&bs[row * 64 + ((q ^ (row & 7)) << 3)]);
      }
#pragma unroll
      for (int i = 0; i < 2; ++i)
#pragma unroll
        for (int j = 0; j < 2; ++j)
          acc[i][j] = mfma_bf16(a[i], b[j], acc[i][j]);
    }
  };

  stage(0, As0, Bs0);
  stage(64, As1, Bs1);
#pragma unroll 1
  for (int s = 0; s < 14; ++s) {
    WAIT_VM4();
    barrier_pinned();
    if (s & 1) comp(As1, Bs1); else comp(As0, Bs0);
    barrier_pinned();
    if (s & 1) stage((s + 2) * 64, As1, Bs1);
    else       stage((s + 2) * 64, As0, Bs0);
  }
  WAIT_VM4();
  barrier_pinned();
  comp(As0, Bs0);
  WAIT_VM0();
  barrier_pinned();
  comp(As1, Bs1);

  const int rgrp = (lane >> 4) * 4;
#pragma unroll
  for (int i = 0; i < 2; ++i) {
    const int nb = n0 + wr * 32 + i * 16 + rgrp;
#pragma unroll
    for (int j = 0; j < 2; ++j) {
      const int mcol = m0 + wc * 32 + j * 16 + (lane & 15);
      const float bb = bias[mcol];
#pragma unroll
      for (int r = 0; r < 4; ++r)
        out[(size_t)(nb + r) * HD + mcol] = acc[i][j][r] + bb;
    }
  }
}

extern "C" void kernel_launch(void* const* d_in, const int* in_sizes, int n_in,
                              void* d_out, int out_size, void* d_ws, size_t ws_size,
                              hipStream_t stream) {
  const float* q  = (const float*)d_in[0];
  const float* k  = (const float*)d_in[1];
  const float* v  = (const float*)d_in[2];
  const float* ab = (const float*)d_in[3];
  const float* Wq = (const float*)d_in[4];
  const float* bq = (const float*)d_in[5];
  const float* Wk = (const float*)d_in[6];
  const float* bk = (const float*)d_in[7];
  const float* Wv = (const float*)d_in[8];
  const float* bv = (const float*)d_in[9];
  const float* Wo = (const float*)d_in[10];
  const float* bo = (const float*)d_in[11];

  unsigned short* qb  = (unsigned short*)d_ws;          // [NT][HD] bf16
  unsigned short* kb  = qb + (size_t)NT * HD;
  unsigned short* vb  = kb + (size_t)NT * HD;
  unsigned short* Wqb = vb + (size_t)NT * HD;           // [HD][HD]
  unsigned short* Wkb = Wqb + (size_t)HD * HD;
  unsigned short* Wvb = Wkb + (size_t)HD * HD;
  unsigned short* Wob = Wvb + (size_t)HD * HD;
  unsigned short* Qh  = Wob + (size_t)HD * HD;          // [NT][HD] bf16 (pre-scaled)
  unsigned short* Kh  = Qh + (size_t)NT * HD;           // [NT][HD]
  unsigned short* Vt  = Kh + (size_t)NT * HD;           // [HD][NT] (transposed)
  unsigned short* ctx = Vt + (size_t)NT * HD;           // [NT][HD]

  cvt_bf16<<<dim3(512, 7), 256, 0, stream>>>(q, k, v, Wq, Wk, Wv, Wo,
                                             qb, kb, vb, Wqb, Wkb, Wvb, Wob);
  proj_gemm<<<dim3(768), 256, 0, stream>>>(
      qb, kb, vb, Wqb, Wkb, Wvb, bq, bk, bv, Qh, Kh, Vt);
  attn_kernel<<<dim3(512), 256, 0, stream>>>(Qh, Kh, Vt, ab, ctx);
  out_gemm<<<dim3(512), 256, 0, stream>>>(ctx, Wob, bo, (float*)d_out);
}